// Round 1
// baseline (224.489 us; speedup 1.0000x reference)
//
#include <hip/hip_runtime.h>
#include <math.h>

// out = gamma * (S * x) + x  ==  (1 + gamma*S) * x
// S = (p+1)/(pi*(N-1)^2) * sum_{i,j in [0,N)} cos(q * atan2(j, i)),  p=2, q=1, N=256
// S is data-independent -> computed on host once; gamma read on device (restored each call).

__global__ __launch_bounds__(256) void zam_scale_kernel(
    const float4* __restrict__ x,
    const float* __restrict__ gamma,
    float4* __restrict__ out,
    float S, int n4)
{
    int i = blockIdx.x * blockDim.x + threadIdx.x;
    if (i < n4) {
        float scale = fmaf(gamma[0], S, 1.0f);
        float4 v = x[i];
        v.x *= scale;
        v.y *= scale;
        v.z *= scale;
        v.w *= scale;
        out[i] = v;
    }
}

static float compute_S() {
    const int N = 256;
    const double p = 2.0, q = 1.0;
    double s = 0.0;
    for (int i = 0; i < N; ++i) {
        for (int j = 0; j < N; ++j) {
            // atan2(0,0) == 0 in C, matching jnp.arctan2(0,0) == 0
            s += cos(q * atan2((double)j, (double)i));
        }
    }
    return (float)(s * (p + 1.0) / (M_PI * (double)(N - 1) * (double)(N - 1)));
}

extern "C" void kernel_launch(void* const* d_in, const int* in_sizes, int n_in,
                              void* d_out, int out_size, void* d_ws, size_t ws_size,
                              hipStream_t stream) {
    const float* x     = (const float*)d_in[0];
    const float* gamma = (const float*)d_in[1];
    float* out         = (float*)d_out;

    static const float S = compute_S();  // deterministic host constant

    int n  = out_size;          // 8*64*256*256 = 33554432
    int n4 = n / 4;             // divisible: 8388608
    int block = 256;
    int grid  = (n4 + block - 1) / block;  // 32768, no tail

    zam_scale_kernel<<<grid, block, 0, stream>>>(
        (const float4*)x, gamma, (float4*)out, S, n4);
}